// Round 1
// baseline (86.981 us; speedup 1.0000x reference)
//
#include <hip/hip_runtime.h>

#define K_ITERS 20
#define MU_CONST 0.05f
#define BN 128

// One block per batch. 256 threads: thread t owns row (t>>1), column half (t&1),
// i.e. the contiguous floats [64*t, 64*t+64) of this batch's 128x128 matrix.
// w stays in registers for all 20 iterations; y lives in LDS.
__global__ __launch_bounds__(256, 4) void nag_kernel(
    const float* __restrict__ w,
    const float* __restrict__ b,
    const float* __restrict__ s_ptr,
    float* __restrict__ out,
    int B)
{
    const int batch = blockIdx.x;
    const int t = threadIdx.x;     // 0..255
    const int r = t >> 1;          // row 0..127
    const int h = t & 1;           // column half

    __shared__ __align__(16) float y_lds[BN];

    // Load this thread's 64 w elements as 16 float4 (fully coalesced over the block).
    const float4* wp = reinterpret_cast<const float4*>(w + (size_t)batch * (BN * BN));
    float4 w4[16];
#pragma unroll
    for (int k = 0; k < 16; ++k)
        w4[k] = wp[t * 16 + k];

    const float s = *s_ptr;
    const float sqms = sqrtf(MU_CONST * s);
    const float alpha = (1.0f - sqms) / (1.0f + sqms);
    const float ap1 = 1.0f + alpha;

    const float b_r = b[(size_t)batch * BN + r];

    float x_r = 0.0f, y_r = 0.0f;

    if (t < BN) y_lds[t] = 0.0f;
    __syncthreads();

    const float4* y4 = reinterpret_cast<const float4*>(y_lds) + h * 16;

    for (int it = 0; it < K_ITERS; ++it) {
        // partial dot of this thread's 64 w elems with y[h*64 .. h*64+63]
        float partial = 0.0f;
#pragma unroll
        for (int k = 0; k < 16; ++k) {
            float4 yv = y4[k];
            partial += w4[k].x * yv.x;
            partial += w4[k].y * yv.y;
            partial += w4[k].z * yv.z;
            partial += w4[k].w * yv.w;
        }
        // pair reduction: lanes 2r and 2r+1 hold the two halves of row r
        float dot = partial + __shfl_xor(partial, 1);

        // NAG update (both lanes of the pair redundantly hold row r state)
        float grad = dot - b_r;
        float xn = y_r - s * grad;
        y_r = ap1 * xn - alpha * x_r;
        x_r = xn;

        __syncthreads();               // all reads of y_lds done
        if (h == 0) y_lds[r] = y_r;
        __syncthreads();               // new y visible
    }

    // Output: x flat (B*N) then y flat (B*N)
    if (h == 0) {
        out[(size_t)batch * BN + r] = x_r;
        out[(size_t)B * BN + (size_t)batch * BN + r] = y_r;
    }
}

extern "C" void kernel_launch(void* const* d_in, const int* in_sizes, int n_in,
                              void* d_out, int out_size, void* d_ws, size_t ws_size,
                              hipStream_t stream) {
    const float* w = (const float*)d_in[0];
    const float* b = (const float*)d_in[1];
    const float* s = (const float*)d_in[2];
    float* out = (float*)d_out;
    const int B = in_sizes[1] / BN;    // 4096
    nag_kernel<<<dim3(B), dim3(256), 0, stream>>>(w, b, s, out, B);
}